// Round 1
// baseline (1006.383 us; speedup 1.0000x reference)
//
#include <hip/hip_runtime.h>
#include <hip/hip_bf16.h>

#define NPIX 16384
#define NVOC 8192

// ws byte offsets
#define WS_BNORM 0u        // 8192 floats
#define WS_ANORM 32768u    // 16384 floats
#define WS_MINV  98304u    // 4*16384 floats
#define WS_MINI  360448u   // 4*16384 ints
#define WS_PART  622592u   // 256 floats

// Replicates numpy pairwise_sum for a 128-element block of squares:
// r0..r7 = x0..x7; unrolled-by-8 accumulation; ((r0+r1)+(r2+r3))+((r4+r5)+(r6+r7))
__device__ __forceinline__ float np_pairwise128_sq(const float* x, int stride) {
  float r[8];
#pragma unroll
  for (int j = 0; j < 8; ++j) {
    float v = x[j * stride];
    r[j] = __fmul_rn(v, v);
  }
#pragma unroll
  for (int i = 1; i < 16; ++i) {
#pragma unroll
    for (int j = 0; j < 8; ++j) {
      float v = x[(i * 8 + j) * stride];
      r[j] = __fadd_rn(r[j], __fmul_rn(v, v));
    }
  }
  return __fadd_rn(__fadd_rn(__fadd_rn(r[0], r[1]), __fadd_rn(r[2], r[3])),
                   __fadd_rn(__fadd_rn(r[4], r[5]), __fadd_rn(r[6], r[7])));
}

// ||codebook_j||^2 for all 8192 codes, numpy summation order.
__global__ __launch_bounds__(256) void k_bnorm(const float* __restrict__ cb,
                                               float* __restrict__ bn) {
  __shared__ float rows[64][257];
  int tid = threadIdx.x;
  int c0 = blockIdx.x * 64;
  for (int r = 0; r < 64; ++r)
    rows[r][tid] = cb[(size_t)(c0 + r) * 256 + tid];
  __syncthreads();
  if (tid < 64) {
    float a = np_pairwise128_sq(&rows[tid][0], 1);
    float b = np_pairwise128_sq(&rows[tid][128], 1);
    bn[c0 + tid] = __fadd_rn(a, b);
  }
}

// ||ze_p||^2 for all 16384 pixels, numpy summation order. Coalesced across lanes.
__global__ __launch_bounds__(256) void k_anorm(const float* __restrict__ ze,
                                               float* __restrict__ an) {
  int p = blockIdx.x * 256 + threadIdx.x;
  int b = p >> 10, hw = p & 1023;
  const float* base = ze + (size_t)b * 262144 + hw;
  float a = np_pairwise128_sq(base, 1024);
  float b2 = np_pairwise128_sq(base + 128 * 1024, 1024);
  an[p] = __fadd_rn(a, b2);
}

// Main distance + argmin kernel.
// Grid: 512 blocks = 128 pixel-blocks (BM=128) x 4 code-splits (2048 codes each).
// 256 threads as 16x16; each thread owns an 8x8 (pixel x code) accumulator tile.
__global__ __launch_bounds__(256, 2) void k_main(const float* __restrict__ ze,
                                                 const float* __restrict__ cb,
                                                 const float* __restrict__ bn,
                                                 const float* __restrict__ an,
                                                 float* __restrict__ minv_ws,
                                                 int* __restrict__ mini_ws) {
  __shared__ float zs[32][128];
  __shared__ float cs[32][128];
  int tid = threadIdx.x;
  int tx = tid & 15, ty = tid >> 4;
  int pb = blockIdx.x >> 2, split = blockIdx.x & 3;
  int p0 = pb * 128;
  int b = p0 >> 10, hw0 = p0 & 1023;
  const float* zebase = ze + (size_t)b * 262144 + hw0;

  float minv[8];
  int mini[8];
#pragma unroll
  for (int i = 0; i < 8; ++i) { minv[i] = 3.4e38f; mini[i] = 0x7fffffff; }

  float Ap[8];
#pragma unroll
  for (int i = 0; i < 8; ++i) Ap[i] = an[p0 + ty * 8 + i];

  for (int jt = split * 16; jt < split * 16 + 16; ++jt) {
    int j0 = jt * 128;
    float acc[8][8];
#pragma unroll
    for (int i = 0; i < 8; ++i)
#pragma unroll
      for (int j = 0; j < 8; ++j) acc[i][j] = 0.f;

    for (int kc = 0; kc < 8; ++kc) {
      __syncthreads();
      // stage ze chunk: zs[k][px], global reads coalesced along px
      {
        int px = tid & 127, khalf = tid >> 7;
#pragma unroll
        for (int i = 0; i < 16; ++i) {
          int k = i * 2 + khalf;
          zs[k][px] = zebase[(size_t)(kc * 32 + k) * 1024 + px];
        }
      }
      // stage codebook chunk transposed: cs[k][q]
      {
        int k4 = tid & 7, qb = tid >> 3;
#pragma unroll
        for (int pass = 0; pass < 4; ++pass) {
          int q = qb + pass * 32;
          const float4 v = *reinterpret_cast<const float4*>(
              cb + (size_t)(j0 + q) * 256 + kc * 32 + k4 * 4);
          cs[k4 * 4 + 0][q] = v.x;
          cs[k4 * 4 + 1][q] = v.y;
          cs[k4 * 4 + 2][q] = v.z;
          cs[k4 * 4 + 3][q] = v.w;
        }
      }
      __syncthreads();
#pragma unroll 4
      for (int k = 0; k < 32; ++k) {
        float za[8], cv[8];
        *reinterpret_cast<float4*>(&za[0]) =
            *reinterpret_cast<const float4*>(&zs[k][ty * 8]);
        *reinterpret_cast<float4*>(&za[4]) =
            *reinterpret_cast<const float4*>(&zs[k][ty * 8 + 4]);
        *reinterpret_cast<float4*>(&cv[0]) =
            *reinterpret_cast<const float4*>(&cs[k][tx * 8]);
        *reinterpret_cast<float4*>(&cv[4]) =
            *reinterpret_cast<const float4*>(&cs[k][tx * 8 + 4]);
#pragma unroll
        for (int pi = 0; pi < 8; ++pi)
#pragma unroll
          for (int jj = 0; jj < 8; ++jj)
            acc[pi][jj] = __builtin_fmaf(za[pi], cv[jj], acc[pi][jj]);
      }
    }
    // scoring: d = (A + B) - 2*dot   (matches numpy rounding structure)
#pragma unroll
    for (int jj = 0; jj < 8; ++jj) {
      int j = j0 + tx * 8 + jj;
      float Bj = bn[j];
#pragma unroll
      for (int pi = 0; pi < 8; ++pi) {
        float t = __fadd_rn(Ap[pi], Bj);
        float d = __fsub_rn(t, 2.0f * acc[pi][jj]);
        if (d < minv[pi] || (d == minv[pi] && j < mini[pi])) {
          minv[pi] = d;
          mini[pi] = j;
        }
      }
    }
  }
  // reduce across the 16 tx-lanes that share the same 8 pixels
#pragma unroll
  for (int off = 1; off < 16; off <<= 1) {
#pragma unroll
    for (int pi = 0; pi < 8; ++pi) {
      float v2 = __shfl_xor(minv[pi], off, 16);
      int i2 = __shfl_xor(mini[pi], off, 16);
      if (v2 < minv[pi] || (v2 == minv[pi] && i2 < mini[pi])) {
        minv[pi] = v2;
        mini[pi] = i2;
      }
    }
  }
  if (tx == 0) {
#pragma unroll
    for (int pi = 0; pi < 8; ++pi) {
      int p = p0 + ty * 8 + pi;
      minv_ws[split * NPIX + p] = minv[pi];
      mini_ws[split * NPIX + p] = mini[pi];
    }
  }
}

// Merge split candidates, gather codebook rows, write zq (NCHW) + indices,
// accumulate deterministic per-block MSE partial sums.
__global__ __launch_bounds__(256) void k_gather(const float* __restrict__ ze,
                                                const float* __restrict__ cb,
                                                const float* __restrict__ minv_ws,
                                                const int* __restrict__ mini_ws,
                                                float* __restrict__ out_zq,
                                                float* __restrict__ out_idx,
                                                float* __restrict__ part) {
  __shared__ float qrow[64][257];
  __shared__ int sidx[64];
  int tid = threadIdx.x;
  int p0 = blockIdx.x * 64;
  int b = p0 >> 10, hw0 = p0 & 1023;
  if (tid < 64) {
    int p = p0 + tid;
    float bv = minv_ws[p];
    int bi = mini_ws[p];
#pragma unroll
    for (int s = 1; s < 4; ++s) {
      float v = minv_ws[s * NPIX + p];
      int ii = mini_ws[s * NPIX + p];
      if (v < bv || (v == bv && ii < bi)) { bv = v; bi = ii; }
    }
    sidx[tid] = bi;
    out_idx[p] = (float)bi;
  }
  __syncthreads();
  for (int r = 0; r < 64; ++r)
    qrow[r][tid] = cb[(size_t)sidx[r] * 256 + tid];
  __syncthreads();
  float lsum = 0.f;
  size_t zbase = (size_t)b * 262144 + hw0;
#pragma unroll 4
  for (int i = 0; i < 64; ++i) {
    int px = tid & 63;
    int c = i * 4 + (tid >> 6);
    float qv = qrow[px][c];
    size_t gi = zbase + (size_t)c * 1024 + px;
    float zev = ze[gi];
    // straight-through estimator, matching reference rounding: ze + (q - ze)
    out_zq[gi] = __fadd_rn(zev, __fsub_rn(qv, zev));
    float d = zev - qv;
    lsum = __builtin_fmaf(d, d, lsum);
  }
#pragma unroll
  for (int off = 32; off; off >>= 1) lsum += __shfl_xor(lsum, off, 64);
  __shared__ float wsum[4];
  if ((tid & 63) == 0) wsum[tid >> 6] = lsum;
  __syncthreads();
  if (tid == 0) part[blockIdx.x] = (wsum[0] + wsum[1]) + (wsum[2] + wsum[3]);
}

__global__ __launch_bounds__(256) void k_final(const float* __restrict__ part,
                                               float* __restrict__ out0) {
  int tid = threadIdx.x;
  float s = part[tid];
#pragma unroll
  for (int off = 32; off; off >>= 1) s += __shfl_xor(s, off, 64);
  __shared__ float wsum[4];
  if ((tid & 63) == 0) wsum[tid >> 6] = s;
  __syncthreads();
  if (tid == 0) {
    float tot = (wsum[0] + wsum[1]) + (wsum[2] + wsum[3]);
    out0[0] = 1.25f * tot / 4194304.0f;
  }
}

extern "C" void kernel_launch(void* const* d_in, const int* in_sizes, int n_in,
                              void* d_out, int out_size, void* d_ws, size_t ws_size,
                              hipStream_t stream) {
  const float* ze = (const float*)d_in[0];
  const float* cb = (const float*)d_in[1];
  float* out = (float*)d_out;
  char* ws = (char*)d_ws;
  float* bn = (float*)(ws + WS_BNORM);
  float* an = (float*)(ws + WS_ANORM);
  float* minv = (float*)(ws + WS_MINV);
  int* mini = (int*)(ws + WS_MINI);
  float* part = (float*)(ws + WS_PART);
  float* out_loss = out;
  float* out_zq = out + 1;
  float* out_idx = out + 1 + 4194304;

  hipLaunchKernelGGL(k_bnorm, dim3(128), dim3(256), 0, stream, cb, bn);
  hipLaunchKernelGGL(k_anorm, dim3(64), dim3(256), 0, stream, ze, an);
  hipLaunchKernelGGL(k_main, dim3(512), dim3(256), 0, stream, ze, cb, bn, an,
                     minv, mini);
  hipLaunchKernelGGL(k_gather, dim3(256), dim3(256), 0, stream, ze, cb, minv,
                     mini, out_zq, out_idx, part);
  hipLaunchKernelGGL(k_final, dim3(1), dim3(256), 0, stream, part, out_loss);
}

// Round 2
// 309.665 us; speedup vs baseline: 3.2499x; 3.2499x over previous
//
#include <hip/hip_runtime.h>
#include <hip/hip_bf16.h>

#define NPIX 16384
#define NVOC 8192
#define KDIM 256

typedef short short8v __attribute__((ext_vector_type(8)));
typedef float floatx4 __attribute__((ext_vector_type(4)));

// ---- ws layout (bytes) ----
#define WS_ZEBF   0u          // 16384*256 bf16 = 8388608
#define WS_CBBF   8388608u    // 8192*256 bf16  = 4194304
#define WS_BN     12582912u   // 8192 f32
#define WS_AN     12615680u   // 16384 f32
#define WS_MIN    12681216u   // 64*16384 f32 = 4194304
#define WS_TAU    16875520u   // 16384 f32
#define WS_CNT    16941056u   // 16384 i32
#define WS_CAND   17006592u   // 16384*32 i32 = 2097152
#define WS_FIDX   19103744u   // 16384 i32
#define WS_BMAX   19169280u   // 1 f32
#define WS_PART   19169536u   // 256 f32

__device__ __forceinline__ short f2bf(float v) {
  __bf16 h = (__bf16)v;  // RNE, same as __float2bfloat16
  return __builtin_bit_cast(short, h);
}

// numpy pairwise-sum of 128 squares (matches np.sum rounding for 256-vectors)
__device__ __forceinline__ float np_pairwise128_sq(const float* x, int stride) {
  float r[8];
#pragma unroll
  for (int j = 0; j < 8; ++j) {
    float v = x[j * stride];
    r[j] = __fmul_rn(v, v);
  }
#pragma unroll
  for (int i = 1; i < 16; ++i) {
#pragma unroll
    for (int j = 0; j < 8; ++j) {
      float v = x[(i * 8 + j) * stride];
      r[j] = __fadd_rn(r[j], __fmul_rn(v, v));
    }
  }
  return __fadd_rn(__fadd_rn(__fadd_rn(r[0], r[1]), __fadd_rn(r[2], r[3])),
                   __fadd_rn(__fadd_rn(r[4], r[5]), __fadd_rn(r[6], r[7])));
}

__global__ __launch_bounds__(256) void k_bnorm(const float* __restrict__ cb,
                                               float* __restrict__ bn) {
  __shared__ float rows[64][257];
  int tid = threadIdx.x;
  int c0 = blockIdx.x * 64;
  for (int r = 0; r < 64; ++r)
    rows[r][tid] = cb[(size_t)(c0 + r) * 256 + tid];
  __syncthreads();
  if (tid < 64) {
    float a = np_pairwise128_sq(&rows[tid][0], 1);
    float b = np_pairwise128_sq(&rows[tid][128], 1);
    bn[c0 + tid] = __fadd_rn(a, b);
  }
}

__global__ __launch_bounds__(256) void k_anorm(const float* __restrict__ ze,
                                               float* __restrict__ an) {
  int p = blockIdx.x * 256 + threadIdx.x;
  int b = p >> 10, hw = p & 1023;
  const float* base = ze + (size_t)b * 262144 + hw;
  float a = np_pairwise128_sq(base, 1024);
  float b2 = np_pairwise128_sq(base + 128 * 1024, 1024);
  an[p] = __fadd_rn(a, b2);
}

__global__ __launch_bounds__(256) void k_bmax(const float* __restrict__ bn,
                                              float* __restrict__ bmax) {
  int tid = threadIdx.x;
  float m = 0.f;
  for (int i = tid; i < NVOC; i += 256) m = fmaxf(m, bn[i]);
#pragma unroll
  for (int off = 32; off; off >>= 1) m = fmaxf(m, __shfl_xor(m, off));
  __shared__ float w4[4];
  if ((tid & 63) == 0) w4[tid >> 6] = m;
  __syncthreads();
  if (tid == 0)
    bmax[0] = sqrtf(fmaxf(fmaxf(w4[0], w4[1]), fmaxf(w4[2], w4[3])));
}

// ze [16][256][1024] fp32 -> zebf [16384][256] bf16 (pixel-major, k contiguous)
__global__ __launch_bounds__(256) void k_cvt_ze(const float* __restrict__ ze,
                                                short* __restrict__ zebf) {
  __shared__ short lds[64][258];
  int tid = threadIdx.x;
  int p0 = blockIdx.x * 64;  // 256 blocks
  int b = p0 >> 10, hw0 = p0 & 1023;
  const float* src = ze + (size_t)b * 262144 + hw0;
  int hw = tid & 63, c4 = tid >> 6;
#pragma unroll 4
  for (int i = 0; i < 64; ++i) {
    int c = i * 4 + c4;
    lds[hw][c] = f2bf(src[(size_t)c * 1024 + hw]);
  }
  __syncthreads();
  int row = tid >> 2, q = tid & 3;
  short* dst = zebf + (size_t)(p0 + row) * 256 + q * 64;
#pragma unroll
  for (int s = 0; s < 8; ++s) {
    short8v v;
#pragma unroll
    for (int e = 0; e < 8; ++e) v[e] = lds[row][q * 64 + s * 8 + e];
    *reinterpret_cast<short8v*>(dst + s * 8) = v;
  }
}

// cb [8192][256] fp32 -> cbbf bf16 same layout
__global__ __launch_bounds__(256) void k_cvt_cb(const float* __restrict__ cb,
                                                short* __restrict__ cbbf) {
  size_t i = ((size_t)blockIdx.x * 256 + threadIdx.x) * 8;  // 1024 blocks
  float4 a = *reinterpret_cast<const float4*>(cb + i);
  float4 b = *reinterpret_cast<const float4*>(cb + i + 4);
  short8v v;
  v[0] = f2bf(a.x); v[1] = f2bf(a.y); v[2] = f2bf(a.z); v[3] = f2bf(a.w);
  v[4] = f2bf(b.x); v[5] = f2bf(b.y); v[6] = f2bf(b.z); v[7] = f2bf(b.w);
  *reinterpret_cast<short8v*>(cbbf + i) = v;
}

// bf16 MFMA distance GEMM. PHASE 0: per-(colblock,pixel) min. PHASE 1: collect
// candidates with t_hat <= tau[p]. Both phases compute bit-identical t_hat.
template <int PHASE>
__global__ __launch_bounds__(256, 2) void k_gemm(const short* __restrict__ zebf,
                                                 const short* __restrict__ cbbf,
                                                 const float* __restrict__ bn,
                                                 const float* __restrict__ tau,
                                                 float* __restrict__ wsmin,
                                                 int* __restrict__ cnt,
                                                 int* __restrict__ cand) {
  __shared__ short As[128 * 64];
  __shared__ short Bs[128 * 64];
  int tid = threadIdx.x;
  int lane = tid & 63, w = tid >> 6;
  int wr = w >> 1, wc = w & 1;
  int mb = blockIdx.x & 127, nb = blockIdx.x >> 7;
  int p0 = mb * 128, n0 = nb * 128;
  int g = lane >> 4, r16 = lane & 15;

  floatx4 acc[4][4];
#pragma unroll
  for (int i = 0; i < 4; ++i)
#pragma unroll
    for (int j = 0; j < 4; ++j) acc[i][j] = floatx4{0.f, 0.f, 0.f, 0.f};

  const short* Aq = zebf + (size_t)p0 * 256;
  const short* Bq = cbbf + (size_t)n0 * 256;
  int srow = tid >> 3, sc16 = tid & 7;

  short8v ra[4], rb[4];
#pragma unroll
  for (int s = 0; s < 4; ++s) {
    int row = s * 32 + srow;
    ra[s] = *reinterpret_cast<const short8v*>(Aq + (size_t)row * 256 + sc16 * 8);
    rb[s] = *reinterpret_cast<const short8v*>(Bq + (size_t)row * 256 + sc16 * 8);
  }

  for (int kc = 0; kc < 4; ++kc) {
    __syncthreads();  // previous chunk's frag reads done
#pragma unroll
    for (int s = 0; s < 4; ++s) {
      int row = s * 32 + srow;
      int off = row * 64 + ((sc16 ^ (row & 7)) * 8);  // T2 XOR swizzle
      *reinterpret_cast<short8v*>(&As[off]) = ra[s];
      *reinterpret_cast<short8v*>(&Bs[off]) = rb[s];
    }
    __syncthreads();
    if (kc < 3) {  // prefetch next chunk under MFMA
#pragma unroll
      for (int s = 0; s < 4; ++s) {
        int row = s * 32 + srow;
        ra[s] = *reinterpret_cast<const short8v*>(
            Aq + (size_t)row * 256 + (kc + 1) * 64 + sc16 * 8);
        rb[s] = *reinterpret_cast<const short8v*>(
            Bq + (size_t)row * 256 + (kc + 1) * 64 + sc16 * 8);
      }
    }
#pragma unroll
    for (int ks = 0; ks < 2; ++ks) {
      short8v af[4], bfr[4];
      int c16 = ks * 4 + g;
#pragma unroll
      for (int rf = 0; rf < 4; ++rf) {
        int row = wr * 64 + rf * 16 + r16;
        af[rf] = *reinterpret_cast<const short8v*>(
            &As[row * 64 + ((c16 ^ (row & 7)) * 8)]);
      }
#pragma unroll
      for (int cf = 0; cf < 4; ++cf) {
        int col = wc * 64 + cf * 16 + r16;
        bfr[cf] = *reinterpret_cast<const short8v*>(
            &Bs[col * 64 + ((c16 ^ (col & 7)) * 8)]);
      }
#pragma unroll
      for (int rf = 0; rf < 4; ++rf)
#pragma unroll
        for (int cf = 0; cf < 4; ++cf)
          acc[rf][cf] = __builtin_amdgcn_mfma_f32_16x16x32_bf16(
              af[rf], bfr[cf], acc[rf][cf], 0, 0, 0);
    }
  }

  float Bj[4];
#pragma unroll
  for (int cf = 0; cf < 4; ++cf) Bj[cf] = bn[n0 + wc * 64 + cf * 16 + r16];

  if constexpr (PHASE == 0) {
    __shared__ float sm[128][2];
    float rowmin[4][4];
#pragma unroll
    for (int rf = 0; rf < 4; ++rf)
#pragma unroll
      for (int r = 0; r < 4; ++r) {
        float mv = 3.4e38f;
#pragma unroll
        for (int cf = 0; cf < 4; ++cf)
          mv = fminf(mv, __builtin_fmaf(-2.0f, acc[rf][cf][r], Bj[cf]));
        rowmin[rf][r] = mv;
      }
#pragma unroll
    for (int off = 1; off < 16; off <<= 1)
#pragma unroll
      for (int rf = 0; rf < 4; ++rf)
#pragma unroll
        for (int r = 0; r < 4; ++r)
          rowmin[rf][r] = fminf(rowmin[rf][r], __shfl_xor(rowmin[rf][r], off));
    __syncthreads();
    if (r16 == 0) {
#pragma unroll
      for (int rf = 0; rf < 4; ++rf)
#pragma unroll
        for (int r = 0; r < 4; ++r)
          sm[wr * 64 + rf * 16 + g * 4 + r][wc] = rowmin[rf][r];
    }
    __syncthreads();
    if (tid < 128)
      wsmin[(size_t)nb * NPIX + p0 + tid] = fminf(sm[tid][0], sm[tid][1]);
  } else {
#pragma unroll
    for (int rf = 0; rf < 4; ++rf)
#pragma unroll
      for (int r = 0; r < 4; ++r) {
        int p = p0 + wr * 64 + rf * 16 + g * 4 + r;
        float tp = tau[p];
#pragma unroll
        for (int cf = 0; cf < 4; ++cf) {
          float t = __builtin_fmaf(-2.0f, acc[rf][cf][r], Bj[cf]);
          if (t <= tp) {
            int old = atomicAdd(&cnt[p], 1);
            if (old < 32) cand[p * 32 + old] = n0 + wc * 64 + cf * 16 + r16;
          }
        }
      }
  }
}

// global min over colblocks -> tau; zero candidate counters (every call)
__global__ __launch_bounds__(256) void k_reduce(const float* __restrict__ wsmin,
                                                const float* __restrict__ an,
                                                const float* __restrict__ bmax,
                                                float* __restrict__ tau,
                                                int* __restrict__ cnt) {
  int p = blockIdx.x * 256 + threadIdx.x;
  float mv = 3.4e38f;
#pragma unroll 8
  for (int c = 0; c < 64; ++c) mv = fminf(mv, wsmin[(size_t)c * NPIX + p]);
  // |t_hat - t| <= ~0.0079*||x||*||y||; window = 2M with slack
  tau[p] = mv + 0.017f * sqrtf(an[p]) * bmax[0] + 2e-4f;
  cnt[p] = 0;
}

// exact fp32 rescore of candidates, replicating round-1's passing arithmetic
__global__ __launch_bounds__(256) void k_rescore(const float* __restrict__ ze,
                                                 const float* __restrict__ cb,
                                                 const float* __restrict__ an,
                                                 const float* __restrict__ bn,
                                                 const int* __restrict__ cnt,
                                                 const int* __restrict__ cand,
                                                 int* __restrict__ fidx) {
  int tid = threadIdx.x;
  int p = blockIdx.x * 4 + (tid >> 6);
  int lane = tid & 63;
  int c = cnt[p];
  int b = p >> 10, hw = p & 1023;
  const float* zr = ze + (size_t)b * 262144 + hw;  // stride 1024 over k
  float ap = an[p];
  float bestd = 3.4e38f;
  int besti = 0x7fffffff;
  if (c <= 32) {
    if (lane < c) {
      int j = cand[p * 32 + lane];
      const float* cr = cb + (size_t)j * 256;
      float acc = 0.f;
#pragma unroll 4
      for (int k = 0; k < 256; ++k)
        acc = __builtin_fmaf(zr[(size_t)k * 1024], cr[k], acc);
      bestd = __fsub_rn(__fadd_rn(ap, bn[j]), 2.0f * acc);
      besti = j;
    }
  } else {  // overflow fallback: full exact scan (statistically never)
    for (int j = lane; j < NVOC; j += 64) {
      const float* cr = cb + (size_t)j * 256;
      float acc = 0.f;
#pragma unroll 4
      for (int k = 0; k < 256; ++k)
        acc = __builtin_fmaf(zr[(size_t)k * 1024], cr[k], acc);
      float d = __fsub_rn(__fadd_rn(ap, bn[j]), 2.0f * acc);
      if (d < bestd || (d == bestd && j < besti)) { bestd = d; besti = j; }
    }
  }
#pragma unroll
  for (int off = 1; off < 64; off <<= 1) {
    float d2 = __shfl_xor(bestd, off);
    int i2 = __shfl_xor(besti, off);
    if (d2 < bestd || (d2 == bestd && i2 < besti)) { bestd = d2; besti = i2; }
  }
  if (lane == 0) fidx[p] = besti;
}

__global__ __launch_bounds__(256) void k_gather(const float* __restrict__ ze,
                                                const float* __restrict__ cb,
                                                const int* __restrict__ fidx,
                                                float* __restrict__ out_zq,
                                                float* __restrict__ out_idx,
                                                float* __restrict__ part) {
  __shared__ float qrow[64][257];
  __shared__ int sidx[64];
  int tid = threadIdx.x;
  int p0 = blockIdx.x * 64;
  int b = p0 >> 10, hw0 = p0 & 1023;
  if (tid < 64) {
    int bi = fidx[p0 + tid];
    sidx[tid] = bi;
    out_idx[p0 + tid] = (float)bi;
  }
  __syncthreads();
  for (int r = 0; r < 64; ++r)
    qrow[r][tid] = cb[(size_t)sidx[r] * 256 + tid];
  __syncthreads();
  float lsum = 0.f;
  size_t zbase = (size_t)b * 262144 + hw0;
#pragma unroll 4
  for (int i = 0; i < 64; ++i) {
    int px = tid & 63;
    int c = i * 4 + (tid >> 6);
    float qv = qrow[px][c];
    size_t gi = zbase + (size_t)c * 1024 + px;
    float zev = ze[gi];
    out_zq[gi] = __fadd_rn(zev, __fsub_rn(qv, zev));
    float d = zev - qv;
    lsum = __builtin_fmaf(d, d, lsum);
  }
#pragma unroll
  for (int off = 32; off; off >>= 1) lsum += __shfl_xor(lsum, off, 64);
  __shared__ float wsum[4];
  if ((tid & 63) == 0) wsum[tid >> 6] = lsum;
  __syncthreads();
  if (tid == 0) part[blockIdx.x] = (wsum[0] + wsum[1]) + (wsum[2] + wsum[3]);
}

__global__ __launch_bounds__(256) void k_final(const float* __restrict__ part,
                                               float* __restrict__ out0) {
  int tid = threadIdx.x;
  float s = part[tid];
#pragma unroll
  for (int off = 32; off; off >>= 1) s += __shfl_xor(s, off, 64);
  __shared__ float wsum[4];
  if ((tid & 63) == 0) wsum[tid >> 6] = s;
  __syncthreads();
  if (tid == 0)
    out0[0] = 1.25f * ((wsum[0] + wsum[1]) + (wsum[2] + wsum[3])) / 4194304.0f;
}

extern "C" void kernel_launch(void* const* d_in, const int* in_sizes, int n_in,
                              void* d_out, int out_size, void* d_ws, size_t ws_size,
                              hipStream_t stream) {
  const float* ze = (const float*)d_in[0];
  const float* cb = (const float*)d_in[1];
  float* out = (float*)d_out;
  char* ws = (char*)d_ws;
  short* zebf = (short*)(ws + WS_ZEBF);
  short* cbbf = (short*)(ws + WS_CBBF);
  float* bn = (float*)(ws + WS_BN);
  float* an = (float*)(ws + WS_AN);
  float* wsmin = (float*)(ws + WS_MIN);
  float* tau = (float*)(ws + WS_TAU);
  int* cnt = (int*)(ws + WS_CNT);
  int* cand = (int*)(ws + WS_CAND);
  int* fidx = (int*)(ws + WS_FIDX);
  float* bmax = (float*)(ws + WS_BMAX);
  float* part = (float*)(ws + WS_PART);
  float* out_loss = out;
  float* out_zq = out + 1;
  float* out_idx = out + 1 + 4194304;

  k_cvt_ze<<<256, 256, 0, stream>>>(ze, zebf);
  k_cvt_cb<<<1024, 256, 0, stream>>>(cb, cbbf);
  k_bnorm<<<128, 256, 0, stream>>>(cb, bn);
  k_anorm<<<64, 256, 0, stream>>>(ze, an);
  k_bmax<<<1, 256, 0, stream>>>(bn, bmax);
  k_gemm<0><<<8192, 256, 0, stream>>>(zebf, cbbf, bn, tau, wsmin, cnt, cand);
  k_reduce<<<64, 256, 0, stream>>>(wsmin, an, bmax, tau, cnt);
  k_gemm<1><<<8192, 256, 0, stream>>>(zebf, cbbf, bn, tau, wsmin, cnt, cand);
  k_rescore<<<4096, 256, 0, stream>>>(ze, cb, an, bn, cnt, cand, fidx);
  k_gather<<<256, 256, 0, stream>>>(ze, cb, fidx, out_zq, out_idx, part);
  k_final<<<1, 256, 0, stream>>>(part, out_loss);
}